// Round 6
// baseline (106.118 us; speedup 1.0000x reference)
//
#include <hip/hip_runtime.h>
#include <hip/hip_bf16.h>
#include <math.h>

#define SLOPE 0.1f
#define B_ 16
#define C_ 64
#define H_ 160
#define W_ 160
#define HW_ (H_*W_)

// ws layout (floats): [0,9216) k[b][c][9] ; [9216,10240) att[b][c]
#define WS_K   0
#define WS_ATT 9216

typedef short bf16x8 __attribute__((ext_vector_type(8)));
typedef float f32x4  __attribute__((ext_vector_type(4)));
typedef unsigned int uint2v __attribute__((ext_vector_type(2)));

__device__ __forceinline__ float lrelu(float x) { return fmaxf(x, SLOPE * x); }
__device__ __forceinline__ unsigned f2bf(float x) {
  union { float f; unsigned u; } c; c.f = x;
  return (c.u + 0x7fffu + ((c.u >> 16) & 1u)) >> 16;
}

__global__ __launch_bounds__(64) void prep_kernel(
    const float* __restrict__ deg,
    const float* __restrict__ W1,
    const float* __restrict__ W2,
    const float* __restrict__ Wd1,
    const float* __restrict__ Wd2,
    float* __restrict__ ws) {
  const int b = blockIdx.x;   // 0..15
  const int j = threadIdx.x;  // 0..63
  __shared__ float sd[64], sh[64], sa[8];
  sd[j] = deg[b * 64 + j];
  __syncthreads();

  float acc = 0.f;
  for (int i = 0; i < 64; ++i) acc = fmaf(sd[i], W1[j * 64 + i], acc);
  sh[j] = lrelu(acc);

  if (j < 8) {
    float s = 0.f;
    for (int i = 0; i < 64; ++i) s = fmaf(sd[i], Wd1[j * 64 + i], s);
    sa[j] = lrelu(s);
  }
  __syncthreads();

  float kv[9];
#pragma unroll
  for (int t = 0; t < 9; ++t) kv[t] = 0.f;
  for (int l = 0; l < 64; ++l) {
    float hl = sh[l];
#pragma unroll
    for (int t = 0; t < 9; ++t) kv[t] = fmaf(hl, W2[(j * 9 + t) * 64 + l], kv[t]);
  }
#pragma unroll
  for (int t = 0; t < 9; ++t) ws[WS_K + (b * 64 + j) * 9 + t] = kv[t];

  float s2 = 0.f;
#pragma unroll
  for (int r = 0; r < 8; ++r) s2 = fmaf(Wd2[j * 8 + r], sa[r], s2);
  ws[WS_ATT + b * 64 + j] = 1.f / (1.f + __expf(-s2));
}

// Tile = 8 rows x 16 cols (128 px) of one batch image.
// Phase 1: thread = (channel c = tid>>2, x-quad q = tid&3). Owns a 4-px-wide
//   x 8-row strip of channel c: 30 INDEPENDENT loads in one burst, 288 FMAs,
//   bf16 results into subtiled LDS T' [cblk][pblk(=row)][16][16].
// Phase 2: MFMA 16x16x32 bf16; B-fragments via ds_read_b64_tr_b16 from T'.
// Epilogue: + bc + feat*att (fp32 global re-read, L2/L3-warm), store.
// LDS 16 KB only -> 8 blocks/CU (32 waves, wave-slot cap). VGPR<=64.
__global__ __launch_bounds__(256, 8) void main_kernel(
    const float* __restrict__ feat,
    const float* __restrict__ Wc,
    const float* __restrict__ bc,
    const float* __restrict__ ws,
    float* __restrict__ out) {
  __shared__ unsigned short Tq[8192];  // 16 KB: [4 cblk][8 pblk][16][16]

  // Chunked XCD swizzle (3200 % 8 == 0).
  const int rb  = blockIdx.x;
  const int bid = (rb & 7) * 400 + (rb >> 3);
  const int b   = bid / 200;
  const int rem = bid - b * 200;
  const int ty  = rem / 10, tx = rem - ty * 10;
  const int x0 = tx * 16, y0 = ty * 8;
  const int tid = threadIdx.x;

  const float* __restrict__ kkp   = ws + WS_K + b * 576;
  const float* __restrict__ attp  = ws + WS_ATT + b * 64;
  const float* __restrict__ plane = feat + (size_t)(b * 64) * HW_;

  // ================= Phase 1: conv, strip-mined =================
  const int c = tid >> 2, q = tid & 3;
  const int xb = x0 + q * 4;
  const int xl = max(xb - 1, 0), xr = min(xb + 4, W_ - 1);
  const float ml = (xb > 0) ? 1.f : 0.f;
  const float mr = (xb + 4 < W_) ? 1.f : 0.f;

  const float* __restrict__ p  = plane + (size_t)c * HW_;
  const float* __restrict__ kc = kkp + c * 9;
  const float4 k03 = *(const float4*)(kc);
  const float4 k47 = *(const float4*)(kc + 4);
  const float  k8  = kc[8];

  // 30 independent loads (one burst), then fold masks in place.
  float  Lr[10], Rr[10];
  float4 Mr[10];
#pragma unroll
  for (int r = 0; r < 10; ++r) {
    const int rg = y0 + r - 1;
    const int rc = min(max(rg, 0), H_ - 1);
    const float* rp = p + rc * W_;
    Lr[r] = rp[xl];
    Mr[r] = *(const float4*)(rp + xb);
    Rr[r] = rp[xr];
  }
#pragma unroll
  for (int r = 0; r < 10; ++r) {
    const int rg = y0 + r - 1;
    const float mrow = (rg >= 0 && rg < H_) ? 1.f : 0.f;
    Lr[r] *= mrow * ml;
    Mr[r].x *= mrow; Mr[r].y *= mrow; Mr[r].z *= mrow; Mr[r].w *= mrow;
    Rr[r] *= mrow * mr;
  }

  const int cblk = c >> 4, crow = c & 15;
  const int tbase = cblk * 2048 + crow * 16 + q * 4;  // ushort units
#pragma unroll
  for (int r = 0; r < 8; ++r) {
    const float t0 = Lr[r],   t1 = Mr[r].x,   t2 = Mr[r].y,   t3 = Mr[r].z,   t4 = Mr[r].w,   t5 = Rr[r];
    const float c0 = Lr[r+1], c1 = Mr[r+1].x, c2 = Mr[r+1].y, c3 = Mr[r+1].z, c4 = Mr[r+1].w, c5 = Rr[r+1];
    const float b0 = Lr[r+2], b1 = Mr[r+2].x, b2 = Mr[r+2].y, b3 = Mr[r+2].z, b4 = Mr[r+2].w, b5 = Rr[r+2];

    float s0 = t0 * k03.x;
    s0 = fmaf(t1, k03.y, s0); s0 = fmaf(t2, k03.z, s0);
    s0 = fmaf(c0, k03.w, s0); s0 = fmaf(c1, k47.x, s0);
    s0 = fmaf(c2, k47.y, s0); s0 = fmaf(b0, k47.z, s0);
    s0 = fmaf(b1, k47.w, s0); s0 = fmaf(b2, k8,    s0);
    float s1 = t1 * k03.x;
    s1 = fmaf(t2, k03.y, s1); s1 = fmaf(t3, k03.z, s1);
    s1 = fmaf(c1, k03.w, s1); s1 = fmaf(c2, k47.x, s1);
    s1 = fmaf(c3, k47.y, s1); s1 = fmaf(b1, k47.z, s1);
    s1 = fmaf(b2, k47.w, s1); s1 = fmaf(b3, k8,    s1);
    float s2 = t2 * k03.x;
    s2 = fmaf(t3, k03.y, s2); s2 = fmaf(t4, k03.z, s2);
    s2 = fmaf(c2, k03.w, s2); s2 = fmaf(c3, k47.x, s2);
    s2 = fmaf(c4, k47.y, s2); s2 = fmaf(b2, k47.z, s2);
    s2 = fmaf(b3, k47.w, s2); s2 = fmaf(b4, k8,    s2);
    float s3 = t3 * k03.x;
    s3 = fmaf(t4, k03.y, s3); s3 = fmaf(t5, k03.z, s3);
    s3 = fmaf(c3, k03.w, s3); s3 = fmaf(c4, k47.x, s3);
    s3 = fmaf(c5, k47.y, s3); s3 = fmaf(b3, k47.z, s3);
    s3 = fmaf(b4, k47.w, s3); s3 = fmaf(b5, k8,    s3);

    uint2v tq;
    tq.x = f2bf(lrelu(s0)) | (f2bf(lrelu(s1)) << 16);
    tq.y = f2bf(lrelu(s2)) | (f2bf(lrelu(s3)) << 16);
    *(uint2v*)&Tq[tbase + r * 256] = tq;
  }
  __syncthreads();

  // ================= Phase 2: MFMA channel mix =================
  const int lane = tid & 63, wid = tid >> 6;
  const int nl = lane & 15, g = lane >> 4;
  const int ochunk = wid * 16;

  union AF { bf16x8 v; unsigned short u[8]; };
  AF a0, a1;
  {
    const float* wr = Wc + (ochunk + nl) * 64 + 4 * g;
    const float4 w00 = *(const float4*)(wr);
    const float4 w01 = *(const float4*)(wr + 16);
    const float4 w10 = *(const float4*)(wr + 32);
    const float4 w11 = *(const float4*)(wr + 48);
    a0.u[0]=f2bf(w00.x); a0.u[1]=f2bf(w00.y); a0.u[2]=f2bf(w00.z); a0.u[3]=f2bf(w00.w);
    a0.u[4]=f2bf(w01.x); a0.u[5]=f2bf(w01.y); a0.u[6]=f2bf(w01.z); a0.u[7]=f2bf(w01.w);
    a1.u[0]=f2bf(w10.x); a1.u[1]=f2bf(w10.y); a1.u[2]=f2bf(w10.z); a1.u[3]=f2bf(w10.w);
    a1.u[4]=f2bf(w11.x); a1.u[5]=f2bf(w11.y); a1.u[6]=f2bf(w11.z); a1.u[7]=f2bf(w11.w);
  }

  const unsigned t_lds = (unsigned)(uintptr_t)(&Tq[0]) + (unsigned)(lane * 8);

  f32x4 acc[8];
#pragma unroll
  for (int nt = 0; nt < 8; ++nt) acc[nt] = (f32x4){0.f, 0.f, 0.f, 0.f};

  union BU { bf16x8 v; uint2v qv[2]; };
#pragma unroll
  for (int nt = 0; nt < 8; ++nt) {
    uint2v r0, r1, r2, r3;
    asm volatile("ds_read_b64_tr_b16 %0, %1 offset:%2" : "=v"(r0) : "v"(t_lds), "i"(nt * 512));
    asm volatile("ds_read_b64_tr_b16 %0, %1 offset:%2" : "=v"(r1) : "v"(t_lds), "i"(4096 + nt * 512));
    asm volatile("ds_read_b64_tr_b16 %0, %1 offset:%2" : "=v"(r2) : "v"(t_lds), "i"(8192 + nt * 512));
    asm volatile("ds_read_b64_tr_b16 %0, %1 offset:%2" : "=v"(r3) : "v"(t_lds), "i"(12288 + nt * 512));
    asm volatile("s_waitcnt lgkmcnt(0)" ::: "memory");
    __builtin_amdgcn_sched_barrier(0);
    BU bu0, bu1;
    bu0.qv[0] = r0; bu0.qv[1] = r1;   // k = 4g+j  and  16+4g+j
    bu1.qv[0] = r2; bu1.qv[1] = r3;   // k = 32+4g+j and 48+4g+j
    acc[nt] = __builtin_amdgcn_mfma_f32_16x16x32_bf16(a0.v, bu0.v, acc[nt], 0, 0, 0);
    acc[nt] = __builtin_amdgcn_mfma_f32_16x16x32_bf16(a1.v, bu1.v, acc[nt], 0, 0, 0);
  }

  // ================= Epilogue: + bias + feat*att (global re-read) =========
  const int ob = ochunk + 4 * g;
  const float4 bcv = *(const float4*)(bc + ob);
  const float4 atv = *(const float4*)(attp + ob);
  float* __restrict__ outb = out + (size_t)(b * 64) * HW_;
#pragma unroll
  for (int nt = 0; nt < 8; ++nt) {
    const int off = (y0 + nt) * W_ + x0 + nl;
    const float f0 = plane[(size_t)(ob + 0) * HW_ + off];
    const float f1 = plane[(size_t)(ob + 1) * HW_ + off];
    const float f2 = plane[(size_t)(ob + 2) * HW_ + off];
    const float f3 = plane[(size_t)(ob + 3) * HW_ + off];
    outb[(size_t)(ob + 0) * HW_ + off] = acc[nt][0] + bcv.x + f0 * atv.x;
    outb[(size_t)(ob + 1) * HW_ + off] = acc[nt][1] + bcv.y + f1 * atv.y;
    outb[(size_t)(ob + 2) * HW_ + off] = acc[nt][2] + bcv.z + f2 * atv.z;
    outb[(size_t)(ob + 3) * HW_ + off] = acc[nt][3] + bcv.w + f3 * atv.w;
  }
}

extern "C" void kernel_launch(void* const* d_in, const int* in_sizes, int n_in,
                              void* d_out, int out_size, void* d_ws, size_t ws_size,
                              hipStream_t stream) {
  const float* feat = (const float*)d_in[0];
  const float* deg  = (const float*)d_in[1];
  const float* W1   = (const float*)d_in[2];
  const float* W2   = (const float*)d_in[3];
  const float* Wc   = (const float*)d_in[4];
  const float* bc   = (const float*)d_in[5];
  const float* Wd1  = (const float*)d_in[6];
  const float* Wd2  = (const float*)d_in[7];
  float* out = (float*)d_out;
  float* ws  = (float*)d_ws;

  prep_kernel<<<dim3(B_), dim3(64), 0, stream>>>(deg, W1, W2, Wd1, Wd2, ws);
  main_kernel<<<dim3(3200), dim3(256), 0, stream>>>(feat, Wc, bc, ws, out);
}

// Round 7
// 98.767 us; speedup vs baseline: 1.0744x; 1.0744x over previous
//
#include <hip/hip_runtime.h>
#include <hip/hip_bf16.h>
#include <math.h>

#define SLOPE 0.1f
#define B_ 16
#define C_ 64
#define H_ 160
#define W_ 160
#define HW_ (H_*W_)

// ws layout (floats): [0,9216) k[b][c][9] ; [9216,10240) att[b][c]
#define WS_K   0
#define WS_ATT 9216

typedef short bf16x8 __attribute__((ext_vector_type(8)));
typedef float f32x4  __attribute__((ext_vector_type(4)));
typedef unsigned int uint2v __attribute__((ext_vector_type(2)));

__device__ __forceinline__ float lrelu(float x) { return fmaxf(x, SLOPE * x); }
__device__ __forceinline__ unsigned f2bf(float x) {
  union { float f; unsigned u; } c; c.f = x;
  return (c.u + 0x7fffu + ((c.u >> 16) & 1u)) >> 16;
}

__global__ __launch_bounds__(64) void prep_kernel(
    const float* __restrict__ deg,
    const float* __restrict__ W1,
    const float* __restrict__ W2,
    const float* __restrict__ Wd1,
    const float* __restrict__ Wd2,
    float* __restrict__ ws) {
  const int b = blockIdx.x;   // 0..15
  const int j = threadIdx.x;  // 0..63
  __shared__ float sd[64], sh[64], sa[8];
  sd[j] = deg[b * 64 + j];
  __syncthreads();

  float acc = 0.f;
  for (int i = 0; i < 64; ++i) acc = fmaf(sd[i], W1[j * 64 + i], acc);
  sh[j] = lrelu(acc);

  if (j < 8) {
    float s = 0.f;
    for (int i = 0; i < 64; ++i) s = fmaf(sd[i], Wd1[j * 64 + i], s);
    sa[j] = lrelu(s);
  }
  __syncthreads();

  float kv[9];
#pragma unroll
  for (int t = 0; t < 9; ++t) kv[t] = 0.f;
  for (int l = 0; l < 64; ++l) {
    float hl = sh[l];
#pragma unroll
    for (int t = 0; t < 9; ++t) kv[t] = fmaf(hl, W2[(j * 9 + t) * 64 + l], kv[t]);
  }
#pragma unroll
  for (int t = 0; t < 9; ++t) ws[WS_K + (b * 64 + j) * 9 + t] = kv[t];

  float s2 = 0.f;
#pragma unroll
  for (int r = 0; r < 8; ++r) s2 = fmaf(Wd2[j * 8 + r], sa[r], s2);
  ws[WS_ATT + b * 64 + j] = 1.f / (1.f + __expf(-s2));
}

// Tile = 8 rows x 16 cols (128 px) of one batch image.
// Phase 1: thread = (channel c = tid>>2, x-quad q = tid&3): 30 independent
//   loads in one burst, 288 FMAs, bf16 -> subtiled LDS T' [cblk][row][16][16].
// Phase 2: per row-tile nt: depth-1 residual prefetch (4 global loads),
//   4x ds_read_b64_tr_b16 + 2x MFMA into a SINGLE f32x4, immediate store.
//   (single acc keeps phase-2 live set ~20 regs -> no spill at cap 80)
// LDS 16 KB, __launch_bounds__(256,6): 6 blocks/CU (75% occ cap), VGPR<=80.
__global__ __launch_bounds__(256, 6) void main_kernel(
    const float* __restrict__ feat,
    const float* __restrict__ Wc,
    const float* __restrict__ bc,
    const float* __restrict__ ws,
    float* __restrict__ out) {
  __shared__ unsigned short Tq[8192];  // 16 KB: [4 cblk][8 row][16][16]

  // Chunked XCD swizzle (3200 % 8 == 0).
  const int rb  = blockIdx.x;
  const int bid = (rb & 7) * 400 + (rb >> 3);
  const int b   = bid / 200;
  const int rem = bid - b * 200;
  const int ty  = rem / 10, tx = rem - ty * 10;
  const int x0 = tx * 16, y0 = ty * 8;
  const int tid = threadIdx.x;

  const float* __restrict__ kkp   = ws + WS_K + b * 576;
  const float* __restrict__ attp  = ws + WS_ATT + b * 64;
  const float* __restrict__ plane = feat + (size_t)(b * 64) * HW_;

  // ================= Phase 1: conv, strip-mined =================
  const int c = tid >> 2, q = tid & 3;
  const int xb = x0 + q * 4;
  const int xl = max(xb - 1, 0), xr = min(xb + 4, W_ - 1);
  const float ml = (xb > 0) ? 1.f : 0.f;
  const float mr = (xb + 4 < W_) ? 1.f : 0.f;

  const float* __restrict__ p  = plane + (size_t)c * HW_;
  const float* __restrict__ kc = kkp + c * 9;
  const float4 k03 = *(const float4*)(kc);
  const float4 k47 = *(const float4*)(kc + 4);
  const float  k8  = kc[8];

  float  Lr[10], Rr[10];
  float4 Mr[10];
#pragma unroll
  for (int r = 0; r < 10; ++r) {
    const int rg = y0 + r - 1;
    const int rc = min(max(rg, 0), H_ - 1);
    const float* rp = p + rc * W_;
    Lr[r] = rp[xl];
    Mr[r] = *(const float4*)(rp + xb);
    Rr[r] = rp[xr];
  }
#pragma unroll
  for (int r = 0; r < 10; ++r) {
    const int rg = y0 + r - 1;
    const float mrow = (rg >= 0 && rg < H_) ? 1.f : 0.f;
    Lr[r] *= mrow * ml;
    Mr[r].x *= mrow; Mr[r].y *= mrow; Mr[r].z *= mrow; Mr[r].w *= mrow;
    Rr[r] *= mrow * mr;
  }

  const int cblk = c >> 4, crow = c & 15;
  const int tbase = cblk * 2048 + crow * 16 + q * 4;  // ushort units
#pragma unroll
  for (int r = 0; r < 8; ++r) {
    const float t0 = Lr[r],   t1 = Mr[r].x,   t2 = Mr[r].y,   t3 = Mr[r].z,   t4 = Mr[r].w,   t5 = Rr[r];
    const float c0 = Lr[r+1], c1 = Mr[r+1].x, c2 = Mr[r+1].y, c3 = Mr[r+1].z, c4 = Mr[r+1].w, c5 = Rr[r+1];
    const float b0 = Lr[r+2], b1 = Mr[r+2].x, b2 = Mr[r+2].y, b3 = Mr[r+2].z, b4 = Mr[r+2].w, b5 = Rr[r+2];

    float s0 = t0 * k03.x;
    s0 = fmaf(t1, k03.y, s0); s0 = fmaf(t2, k03.z, s0);
    s0 = fmaf(c0, k03.w, s0); s0 = fmaf(c1, k47.x, s0);
    s0 = fmaf(c2, k47.y, s0); s0 = fmaf(b0, k47.z, s0);
    s0 = fmaf(b1, k47.w, s0); s0 = fmaf(b2, k8,    s0);
    float s1 = t1 * k03.x;
    s1 = fmaf(t2, k03.y, s1); s1 = fmaf(t3, k03.z, s1);
    s1 = fmaf(c1, k03.w, s1); s1 = fmaf(c2, k47.x, s1);
    s1 = fmaf(c3, k47.y, s1); s1 = fmaf(b1, k47.z, s1);
    s1 = fmaf(b2, k47.w, s1); s1 = fmaf(b3, k8,    s1);
    float s2 = t2 * k03.x;
    s2 = fmaf(t3, k03.y, s2); s2 = fmaf(t4, k03.z, s2);
    s2 = fmaf(c2, k03.w, s2); s2 = fmaf(c3, k47.x, s2);
    s2 = fmaf(c4, k47.y, s2); s2 = fmaf(b2, k47.z, s2);
    s2 = fmaf(b3, k47.w, s2); s2 = fmaf(b4, k8,    s2);
    float s3 = t3 * k03.x;
    s3 = fmaf(t4, k03.y, s3); s3 = fmaf(t5, k03.z, s3);
    s3 = fmaf(c3, k03.w, s3); s3 = fmaf(c4, k47.x, s3);
    s3 = fmaf(c5, k47.y, s3); s3 = fmaf(b3, k47.z, s3);
    s3 = fmaf(b4, k47.w, s3); s3 = fmaf(b5, k8,    s3);

    uint2v tq;
    tq.x = f2bf(lrelu(s0)) | (f2bf(lrelu(s1)) << 16);
    tq.y = f2bf(lrelu(s2)) | (f2bf(lrelu(s3)) << 16);
    *(uint2v*)&Tq[tbase + r * 256] = tq;
  }
  __syncthreads();

  // ================= Phase 2: MFMA + fused epilogue =================
  const int lane = tid & 63, wid = tid >> 6;
  const int nl = lane & 15, g = lane >> 4;
  const int ochunk = wid * 16;

  union AF { bf16x8 v; unsigned short u[8]; };
  AF a0, a1;
  {
    const float* wr = Wc + (ochunk + nl) * 64 + 4 * g;
    const float4 w00 = *(const float4*)(wr);
    const float4 w01 = *(const float4*)(wr + 16);
    const float4 w10 = *(const float4*)(wr + 32);
    const float4 w11 = *(const float4*)(wr + 48);
    a0.u[0]=f2bf(w00.x); a0.u[1]=f2bf(w00.y); a0.u[2]=f2bf(w00.z); a0.u[3]=f2bf(w00.w);
    a0.u[4]=f2bf(w01.x); a0.u[5]=f2bf(w01.y); a0.u[6]=f2bf(w01.z); a0.u[7]=f2bf(w01.w);
    a1.u[0]=f2bf(w10.x); a1.u[1]=f2bf(w10.y); a1.u[2]=f2bf(w10.z); a1.u[3]=f2bf(w10.w);
    a1.u[4]=f2bf(w11.x); a1.u[5]=f2bf(w11.y); a1.u[6]=f2bf(w11.z); a1.u[7]=f2bf(w11.w);
  }

  const unsigned t_lds = (unsigned)(uintptr_t)(&Tq[0]) + (unsigned)(lane * 8);

  const int ob = ochunk + 4 * g;
  const float4 bcv = *(const float4*)(bc + ob);
  const float4 atv = *(const float4*)(attp + ob);
  const float* __restrict__ rbase = plane + (size_t)ob * HW_;
  float* __restrict__ obase = out + (size_t)(b * 64 + ob) * HW_;

  // depth-1 residual prefetch for nt=0
  int off_c = y0 * W_ + x0 + nl;
  float p0 = rbase[off_c];
  float p1 = rbase[off_c + HW_];
  float p2 = rbase[off_c + 2 * HW_];
  float p3 = rbase[off_c + 3 * HW_];

  union BU { bf16x8 v; uint2v qv[2]; };
#pragma unroll
  for (int nt = 0; nt < 8; ++nt) {
    // issue next row-tile's residual loads (hide under tr_read+MFMA)
    float n0 = 0.f, n1 = 0.f, n2 = 0.f, n3 = 0.f;
    const int off_n = off_c + W_;
    if (nt < 7) {
      n0 = rbase[off_n];
      n1 = rbase[off_n + HW_];
      n2 = rbase[off_n + 2 * HW_];
      n3 = rbase[off_n + 3 * HW_];
    }

    uint2v r0, r1, r2, r3;
    asm volatile("ds_read_b64_tr_b16 %0, %1 offset:%2" : "=v"(r0) : "v"(t_lds), "i"(nt * 512));
    asm volatile("ds_read_b64_tr_b16 %0, %1 offset:%2" : "=v"(r1) : "v"(t_lds), "i"(4096 + nt * 512));
    asm volatile("ds_read_b64_tr_b16 %0, %1 offset:%2" : "=v"(r2) : "v"(t_lds), "i"(8192 + nt * 512));
    asm volatile("ds_read_b64_tr_b16 %0, %1 offset:%2" : "=v"(r3) : "v"(t_lds), "i"(12288 + nt * 512));
    asm volatile("s_waitcnt lgkmcnt(0)" ::: "memory");
    __builtin_amdgcn_sched_barrier(0);
    BU bu0, bu1;
    bu0.qv[0] = r0; bu0.qv[1] = r1;   // k = 4g+j  and  16+4g+j
    bu1.qv[0] = r2; bu1.qv[1] = r3;   // k = 32+4g+j and 48+4g+j
    f32x4 acc = (f32x4){0.f, 0.f, 0.f, 0.f};
    acc = __builtin_amdgcn_mfma_f32_16x16x32_bf16(a0.v, bu0.v, acc, 0, 0, 0);
    acc = __builtin_amdgcn_mfma_f32_16x16x32_bf16(a1.v, bu1.v, acc, 0, 0, 0);

    // fused epilogue: + bias + feat*att, store now
    obase[off_c]           = acc[0] + bcv.x + p0 * atv.x;
    obase[off_c + HW_]     = acc[1] + bcv.y + p1 * atv.y;
    obase[off_c + 2 * HW_] = acc[2] + bcv.z + p2 * atv.z;
    obase[off_c + 3 * HW_] = acc[3] + bcv.w + p3 * atv.w;

    p0 = n0; p1 = n1; p2 = n2; p3 = n3;
    off_c = off_n;
  }
}

extern "C" void kernel_launch(void* const* d_in, const int* in_sizes, int n_in,
                              void* d_out, int out_size, void* d_ws, size_t ws_size,
                              hipStream_t stream) {
  const float* feat = (const float*)d_in[0];
  const float* deg  = (const float*)d_in[1];
  const float* W1   = (const float*)d_in[2];
  const float* W2   = (const float*)d_in[3];
  const float* Wc   = (const float*)d_in[4];
  const float* bc   = (const float*)d_in[5];
  const float* Wd1  = (const float*)d_in[6];
  const float* Wd2  = (const float*)d_in[7];
  float* out = (float*)d_out;
  float* ws  = (float*)d_ws;

  prep_kernel<<<dim3(B_), dim3(64), 0, stream>>>(deg, W1, W2, Wd1, Wd2, ws);
  main_kernel<<<dim3(3200), dim3(256), 0, stream>>>(feat, Wc, bc, ws, out);
}

// Round 8
// 95.514 us; speedup vs baseline: 1.1110x; 1.0341x over previous
//
#include <hip/hip_runtime.h>
#include <hip/hip_bf16.h>
#include <math.h>

#define SLOPE 0.1f
#define B_ 16
#define C_ 64
#define H_ 160
#define W_ 160
#define HW_ (H_*W_)

// ws layout (floats): [0,9216) k[b][c][9] ; [9216,10240) att[b][c]
#define WS_K   0
#define WS_ATT 9216

typedef short bf16x8 __attribute__((ext_vector_type(8)));
typedef float f32x4  __attribute__((ext_vector_type(4)));
typedef unsigned int uint2v __attribute__((ext_vector_type(2)));

__device__ __forceinline__ float lrelu(float x) { return fmaxf(x, SLOPE * x); }
__device__ __forceinline__ unsigned f2bf(float x) {
  union { float f; unsigned u; } c; c.f = x;
  return (c.u + 0x7fffu + ((c.u >> 16) & 1u)) >> 16;
}

__global__ __launch_bounds__(64) void prep_kernel(
    const float* __restrict__ deg,
    const float* __restrict__ W1,
    const float* __restrict__ W2,
    const float* __restrict__ Wd1,
    const float* __restrict__ Wd2,
    float* __restrict__ ws) {
  const int b = blockIdx.x;   // 0..15
  const int j = threadIdx.x;  // 0..63
  __shared__ float sd[64], sh[64], sa[8];
  sd[j] = deg[b * 64 + j];
  __syncthreads();

  float acc = 0.f;
  for (int i = 0; i < 64; ++i) acc = fmaf(sd[i], W1[j * 64 + i], acc);
  sh[j] = lrelu(acc);

  if (j < 8) {
    float s = 0.f;
    for (int i = 0; i < 64; ++i) s = fmaf(sd[i], Wd1[j * 64 + i], s);
    sa[j] = lrelu(s);
  }
  __syncthreads();

  float kv[9];
#pragma unroll
  for (int t = 0; t < 9; ++t) kv[t] = 0.f;
  for (int l = 0; l < 64; ++l) {
    float hl = sh[l];
#pragma unroll
    for (int t = 0; t < 9; ++t) kv[t] = fmaf(hl, W2[(j * 9 + t) * 64 + l], kv[t]);
  }
#pragma unroll
  for (int t = 0; t < 9; ++t) ws[WS_K + (b * 64 + j) * 9 + t] = kv[t];

  float s2 = 0.f;
#pragma unroll
  for (int r = 0; r < 8; ++r) s2 = fmaf(Wd2[j * 8 + r], sa[r], s2);
  ws[WS_ATT + b * 64 + j] = 1.f / (1.f + __expf(-s2));
}

// Tile = 8 rows x 32 cols (256 px), 512 threads, one batch image.
// Phase 1: thread = (channel c = tid>>3, x-quad q = tid&7): 30 independent
//   global loads in ONE burst, 288 FMAs, bf16 -> subtiled LDS
//   T [4 cblk][16 nt][16 ch][16 px] (32 KB).
// Phase 2: 8 waves = 4 out-ch chunks x 2 pixel halves. All global reads as
//   two 16-load bursts pinned between sched_barrier fences; MFMA via
//   ds_read_b64_tr_b16; fused +bias +feat*att epilogue, full-line stores.
__global__ __launch_bounds__(512, 6) void main_kernel(
    const float* __restrict__ feat,
    const float* __restrict__ Wc,
    const float* __restrict__ bc,
    const float* __restrict__ ws,
    float* __restrict__ out) {
  __shared__ unsigned short Tq[16384];  // 32 KB

  // Chunked XCD swizzle (1600 % 8 == 0).
  const int rb  = blockIdx.x;
  const int bid = (rb & 7) * 200 + (rb >> 3);
  const int b   = bid / 100;
  const int rem = bid - b * 100;
  const int ty  = rem / 5, tx = rem - ty * 5;
  const int x0 = tx * 32, y0 = ty * 8;
  const int tid = threadIdx.x;

  const float* __restrict__ kkp   = ws + WS_K + b * 576;
  const float* __restrict__ attp  = ws + WS_ATT + b * 64;
  const float* __restrict__ plane = feat + (size_t)(b * 64) * HW_;

  // ================= Phase 1: conv, strip-mined =================
  const int c = tid >> 3, q = tid & 7;
  const int xb = x0 + q * 4;
  const int xl = max(xb - 1, 0), xr = min(xb + 4, W_ - 1);
  const float ml = (xb > 0) ? 1.f : 0.f;
  const float mr = (xb + 4 < W_) ? 1.f : 0.f;

  const float* __restrict__ p  = plane + (size_t)c * HW_;
  const float* __restrict__ kc = kkp + c * 9;
  const float4 k03 = *(const float4*)(kc);
  const float4 k47 = *(const float4*)(kc + 4);
  const float  k8  = kc[8];

  float  Lr[10], Rr[10];
  float4 Mr[10];
#pragma unroll
  for (int r = 0; r < 10; ++r) {
    const int rg = y0 + r - 1;
    const int rc = min(max(rg, 0), H_ - 1);
    const float* rp = p + rc * W_;
    Lr[r] = rp[xl];
    Mr[r] = *(const float4*)(rp + xb);
    Rr[r] = rp[xr];
  }
#pragma unroll
  for (int r = 0; r < 10; ++r) {
    const int rg = y0 + r - 1;
    const float mrow = (rg >= 0 && rg < H_) ? 1.f : 0.f;
    Lr[r] *= mrow * ml;
    Mr[r].x *= mrow; Mr[r].y *= mrow; Mr[r].z *= mrow; Mr[r].w *= mrow;
    Rr[r] *= mrow * mr;
  }

  const int cblk = c >> 4, crow = c & 15;
  // T ushort index: cblk*4096 + nt*256 + ch*16 + px ; nt = r*2 + (q>>2)
  const int tbase = cblk * 4096 + (q >> 2) * 256 + crow * 16 + (q & 3) * 4;
#pragma unroll
  for (int r = 0; r < 8; ++r) {
    const float t0 = Lr[r],   t1 = Mr[r].x,   t2 = Mr[r].y,   t3 = Mr[r].z,   t4 = Mr[r].w,   t5 = Rr[r];
    const float c0 = Lr[r+1], c1 = Mr[r+1].x, c2 = Mr[r+1].y, c3 = Mr[r+1].z, c4 = Mr[r+1].w, c5 = Rr[r+1];
    const float b0 = Lr[r+2], b1 = Mr[r+2].x, b2 = Mr[r+2].y, b3 = Mr[r+2].z, b4 = Mr[r+2].w, b5 = Rr[r+2];

    float s0 = t0 * k03.x;
    s0 = fmaf(t1, k03.y, s0); s0 = fmaf(t2, k03.z, s0);
    s0 = fmaf(c0, k03.w, s0); s0 = fmaf(c1, k47.x, s0);
    s0 = fmaf(c2, k47.y, s0); s0 = fmaf(b0, k47.z, s0);
    s0 = fmaf(b1, k47.w, s0); s0 = fmaf(b2, k8,    s0);
    float s1 = t1 * k03.x;
    s1 = fmaf(t2, k03.y, s1); s1 = fmaf(t3, k03.z, s1);
    s1 = fmaf(c1, k03.w, s1); s1 = fmaf(c2, k47.x, s1);
    s1 = fmaf(c3, k47.y, s1); s1 = fmaf(b1, k47.z, s1);
    s1 = fmaf(b2, k47.w, s1); s1 = fmaf(b3, k8,    s1);
    float s2 = t2 * k03.x;
    s2 = fmaf(t3, k03.y, s2); s2 = fmaf(t4, k03.z, s2);
    s2 = fmaf(c2, k03.w, s2); s2 = fmaf(c3, k47.x, s2);
    s2 = fmaf(c4, k47.y, s2); s2 = fmaf(b2, k47.z, s2);
    s2 = fmaf(b3, k47.w, s2); s2 = fmaf(b4, k8,    s2);
    float s3 = t3 * k03.x;
    s3 = fmaf(t4, k03.y, s3); s3 = fmaf(t5, k03.z, s3);
    s3 = fmaf(c3, k03.w, s3); s3 = fmaf(c4, k47.x, s3);
    s3 = fmaf(c5, k47.y, s3); s3 = fmaf(b3, k47.z, s3);
    s3 = fmaf(b4, k47.w, s3); s3 = fmaf(b5, k8,    s3);

    uint2v tq;
    tq.x = f2bf(lrelu(s0)) | (f2bf(lrelu(s1)) << 16);
    tq.y = f2bf(lrelu(s2)) | (f2bf(lrelu(s3)) << 16);
    *(uint2v*)&Tq[tbase + r * 512] = tq;
  }
  __syncthreads();

  // ================= Phase 2: MFMA channel mix =================
  const int lane = tid & 63, wid = tid >> 6;
  const int nl = lane & 15, g = lane >> 4;
  const int ochunk = (wid & 3) * 16;  // out-channel chunk
  const int nh = wid >> 2;            // pixel half: nt = nh*8 + i

  union AF { bf16x8 v; unsigned short u[8]; };
  AF a0, a1;
  {
    const float* wr = Wc + (ochunk + nl) * 64 + 4 * g;
    const float4 w00 = *(const float4*)(wr);
    const float4 w01 = *(const float4*)(wr + 16);
    const float4 w10 = *(const float4*)(wr + 32);
    const float4 w11 = *(const float4*)(wr + 48);
    a0.u[0]=f2bf(w00.x); a0.u[1]=f2bf(w00.y); a0.u[2]=f2bf(w00.z); a0.u[3]=f2bf(w00.w);
    a0.u[4]=f2bf(w01.x); a0.u[5]=f2bf(w01.y); a0.u[6]=f2bf(w01.z); a0.u[7]=f2bf(w01.w);
    a1.u[0]=f2bf(w10.x); a1.u[1]=f2bf(w10.y); a1.u[2]=f2bf(w10.z); a1.u[3]=f2bf(w10.w);
    a1.u[4]=f2bf(w11.x); a1.u[5]=f2bf(w11.y); a1.u[6]=f2bf(w11.z); a1.u[7]=f2bf(w11.w);
  }

  const unsigned t_lds = (unsigned)(uintptr_t)(&Tq[0]) + (unsigned)(lane * 8 + nh * 4096);

  const int ob = ochunk + 4 * g;
  const float4 bcv = *(const float4*)(bc + ob);
  const float4 atv = *(const float4*)(attp + ob);
  const float* __restrict__ rbase = plane + (size_t)ob * HW_;
  float* __restrict__ obase = out + (size_t)(b * 64 + ob) * HW_;

  union BU { bf16x8 v; uint2v qv[2]; };
  // i local (0..7): global nt = nh*8+i; pixel = (row nh*4 + (i>>1), col (i&1)*16 + nl)
#define ROWOFF(i) ((y0 + nh * 4 + ((i) >> 1)) * W_ + x0 + ((i) & 1) * 16 + nl)
#define TRMFMA(I, ACC) do { \
    uint2v r0, r1, r2, r3; \
    asm volatile("ds_read_b64_tr_b16 %0, %1 offset:%2" : "=v"(r0) : "v"(t_lds), "i"((I) * 512)); \
    asm volatile("ds_read_b64_tr_b16 %0, %1 offset:%2" : "=v"(r1) : "v"(t_lds), "i"(8192 + (I) * 512)); \
    asm volatile("ds_read_b64_tr_b16 %0, %1 offset:%2" : "=v"(r2) : "v"(t_lds), "i"(16384 + (I) * 512)); \
    asm volatile("ds_read_b64_tr_b16 %0, %1 offset:%2" : "=v"(r3) : "v"(t_lds), "i"(24576 + (I) * 512)); \
    asm volatile("s_waitcnt lgkmcnt(0)" ::: "memory"); \
    __builtin_amdgcn_sched_barrier(0); \
    BU bu0, bu1; \
    bu0.qv[0] = r0; bu0.qv[1] = r1; \
    bu1.qv[0] = r2; bu1.qv[1] = r3; \
    ACC = __builtin_amdgcn_mfma_f32_16x16x32_bf16(a0.v, bu0.v, ACC, 0, 0, 0); \
    ACC = __builtin_amdgcn_mfma_f32_16x16x32_bf16(a1.v, bu1.v, ACC, 0, 0, 0); \
  } while (0)

  // ---- burst A: residual loads for local rows 0..3 ----
  float prA[16];
#pragma unroll
  for (int i = 0; i < 4; ++i) {
    const int off = ROWOFF(i);
#pragma unroll
    for (int j = 0; j < 4; ++j) prA[i * 4 + j] = rbase[(size_t)j * HW_ + off];
  }

  f32x4 accA[4];
#pragma unroll
  for (int i = 0; i < 4; ++i) {
    accA[i] = (f32x4){0.f, 0.f, 0.f, 0.f};
    TRMFMA(i, accA[i]);
  }

  // ---- burst B: residual loads for local rows 4..7 (in flight over stores A + MFMA B) ----
  float prB[16];
#pragma unroll
  for (int i = 0; i < 4; ++i) {
    const int off = ROWOFF(i + 4);
#pragma unroll
    for (int j = 0; j < 4; ++j) prB[i * 4 + j] = rbase[(size_t)j * HW_ + off];
  }

  // ---- combine + store A ----
#pragma unroll
  for (int i = 0; i < 4; ++i) {
    const int off = ROWOFF(i);
    obase[off]                     = accA[i][0] + bcv.x + prA[i * 4 + 0] * atv.x;
    obase[(size_t)1 * HW_ + off]   = accA[i][1] + bcv.y + prA[i * 4 + 1] * atv.y;
    obase[(size_t)2 * HW_ + off]   = accA[i][2] + bcv.z + prA[i * 4 + 2] * atv.z;
    obase[(size_t)3 * HW_ + off]   = accA[i][3] + bcv.w + prA[i * 4 + 3] * atv.w;
  }

  f32x4 accB[4];
#pragma unroll
  for (int i = 0; i < 4; ++i) {
    accB[i] = (f32x4){0.f, 0.f, 0.f, 0.f};
    TRMFMA(i + 4, accB[i]);
  }

  // ---- combine + store B ----
#pragma unroll
  for (int i = 0; i < 4; ++i) {
    const int off = ROWOFF(i + 4);
    obase[off]                     = accB[i][0] + bcv.x + prB[i * 4 + 0] * atv.x;
    obase[(size_t)1 * HW_ + off]   = accB[i][1] + bcv.y + prB[i * 4 + 1] * atv.y;
    obase[(size_t)2 * HW_ + off]   = accB[i][2] + bcv.z + prB[i * 4 + 2] * atv.z;
    obase[(size_t)3 * HW_ + off]   = accB[i][3] + bcv.w + prB[i * 4 + 3] * atv.w;
  }
#undef TRMFMA
#undef ROWOFF
}

extern "C" void kernel_launch(void* const* d_in, const int* in_sizes, int n_in,
                              void* d_out, int out_size, void* d_ws, size_t ws_size,
                              hipStream_t stream) {
  const float* feat = (const float*)d_in[0];
  const float* deg  = (const float*)d_in[1];
  const float* W1   = (const float*)d_in[2];
  const float* W2   = (const float*)d_in[3];
  const float* Wc   = (const float*)d_in[4];
  const float* bc   = (const float*)d_in[5];
  const float* Wd1  = (const float*)d_in[6];
  const float* Wd2  = (const float*)d_in[7];
  float* out = (float*)d_out;
  float* ws  = (float*)d_ws;

  prep_kernel<<<dim3(B_), dim3(64), 0, stream>>>(deg, W1, W2, Wd1, Wd2, ws);
  main_kernel<<<dim3(1600), dim3(512), 0, stream>>>(feat, Wc, bc, ws, out);
}

// Round 9
// 77.771 us; speedup vs baseline: 1.3645x; 1.2282x over previous
//
#include <hip/hip_runtime.h>
#include <hip/hip_bf16.h>
#include <math.h>

#define SLOPE 0.1f
#define B_ 16
#define C_ 64
#define H_ 160
#define W_ 160
#define HW_ (H_*W_)

// ws layout (floats): [0,9216) k[b][c][9] ; [9216,10240) att[b][c]
#define WS_K   0
#define WS_ATT 9216

typedef short bf16x8 __attribute__((ext_vector_type(8)));
typedef float f32x4  __attribute__((ext_vector_type(4)));
typedef unsigned int uint2v __attribute__((ext_vector_type(2)));

__device__ __forceinline__ float lrelu(float x) { return fmaxf(x, SLOPE * x); }
__device__ __forceinline__ unsigned f2bf(float x) {
  union { float f; unsigned u; } c; c.f = x;
  return (c.u + 0x7fffu + ((c.u >> 16) & 1u)) >> 16;
}

__global__ __launch_bounds__(64) void prep_kernel(
    const float* __restrict__ deg,
    const float* __restrict__ W1,
    const float* __restrict__ W2,
    const float* __restrict__ Wd1,
    const float* __restrict__ Wd2,
    float* __restrict__ ws) {
  const int b = blockIdx.x;   // 0..15
  const int j = threadIdx.x;  // 0..63
  __shared__ float sd[64], sh[64], sa[8];
  sd[j] = deg[b * 64 + j];
  __syncthreads();

  float acc = 0.f;
  for (int i = 0; i < 64; ++i) acc = fmaf(sd[i], W1[j * 64 + i], acc);
  sh[j] = lrelu(acc);

  if (j < 8) {
    float s = 0.f;
    for (int i = 0; i < 64; ++i) s = fmaf(sd[i], Wd1[j * 64 + i], s);
    sa[j] = lrelu(s);
  }
  __syncthreads();

  float kv[9];
#pragma unroll
  for (int t = 0; t < 9; ++t) kv[t] = 0.f;
  for (int l = 0; l < 64; ++l) {
    float hl = sh[l];
#pragma unroll
    for (int t = 0; t < 9; ++t) kv[t] = fmaf(hl, W2[(j * 9 + t) * 64 + l], kv[t]);
  }
#pragma unroll
  for (int t = 0; t < 9; ++t) ws[WS_K + (b * 64 + j) * 9 + t] = kv[t];

  float s2 = 0.f;
#pragma unroll
  for (int r = 0; r < 8; ++r) s2 = fmaf(Wd2[j * 8 + r], sa[r], s2);
  ws[WS_ATT + b * 64 + j] = 1.f / (1.f + __expf(-s2));
}

// Tile = 8 rows x 16 cols (128 px) of one batch image.
// Phase 1: thread = (channel c = tid>>2, x-quad q = tid&3). 30 independent
//   loads issued as ONE burst whose results are pinned live by an asm
//   barrier -> compiler must emit all loads back-to-back with a single
//   s_waitcnt (one latency exposure). 288 FMAs -> bf16 into subtiled LDS
//   T' [cblk][row][16][16]; center taps into F' (residual source).
// Phase 2: MFMA 16x16x32 bf16 via ds_read_b64_tr_b16 from T'.
// Epilogue: + bc + F'*att from LDS (no global re-read), store.
__global__ __launch_bounds__(256, 4) void main_kernel(
    const float* __restrict__ feat,
    const float* __restrict__ Wc,
    const float* __restrict__ bc,
    const float* __restrict__ ws,
    float* __restrict__ out) {
  __shared__ unsigned short Tq[8192];  // 16 KB: [4 cblk][8 row][16][16]
  __shared__ unsigned short Fq[8192];  // 16 KB: same layout

  // Chunked XCD swizzle (3200 % 8 == 0).
  const int rb  = blockIdx.x;
  const int bid = (rb & 7) * 400 + (rb >> 3);
  const int b   = bid / 200;
  const int rem = bid - b * 200;
  const int ty  = rem / 10, tx = rem - ty * 10;
  const int x0 = tx * 16, y0 = ty * 8;
  const int tid = threadIdx.x;

  const float* __restrict__ kkp   = ws + WS_K + b * 576;
  const float* __restrict__ attp  = ws + WS_ATT + b * 64;
  const float* __restrict__ plane = feat + (size_t)(b * 64) * HW_;

  // ================= Phase 1: conv, strip-mined, pinned burst ============
  const int c = tid >> 2, q = tid & 3;
  const int xb = x0 + q * 4;
  const int xl = max(xb - 1, 0), xr = min(xb + 4, W_ - 1);
  const float ml = (xb > 0) ? 1.f : 0.f;
  const float mr = (xb + 4 < W_) ? 1.f : 0.f;

  const float* __restrict__ p  = plane + (size_t)c * HW_;
  const float* __restrict__ kc = kkp + c * 9;
  const float4 k03 = *(const float4*)(kc);
  const float4 k47 = *(const float4*)(kc + 4);
  const float  k8  = kc[8];

  float Lr[10], Rr[10];
  f32x4 Mr[10];
#pragma unroll
  for (int r = 0; r < 10; ++r) {
    const int rg = y0 + r - 1;
    const int rc = min(max(rg, 0), H_ - 1);
    const float* rp = p + rc * W_;
    Lr[r] = rp[xl];
    Mr[r] = *(const f32x4*)(rp + xb);
    Rr[r] = rp[xr];
  }
  // Liveness pin: all 30 results must exist here simultaneously -> the
  // compiler issues all loads first, one s_waitcnt before this point.
  asm volatile("" :
      "+v"(Lr[0]), "+v"(Lr[1]), "+v"(Lr[2]), "+v"(Lr[3]), "+v"(Lr[4]),
      "+v"(Lr[5]), "+v"(Lr[6]), "+v"(Lr[7]), "+v"(Lr[8]), "+v"(Lr[9]),
      "+v"(Rr[0]), "+v"(Rr[1]), "+v"(Rr[2]), "+v"(Rr[3]), "+v"(Rr[4]),
      "+v"(Rr[5]), "+v"(Rr[6]), "+v"(Rr[7]), "+v"(Rr[8]), "+v"(Rr[9]),
      "+v"(Mr[0]), "+v"(Mr[1]), "+v"(Mr[2]), "+v"(Mr[3]), "+v"(Mr[4]),
      "+v"(Mr[5]), "+v"(Mr[6]), "+v"(Mr[7]), "+v"(Mr[8]), "+v"(Mr[9]));

#pragma unroll
  for (int r = 0; r < 10; ++r) {
    const int rg = y0 + r - 1;
    const float mrow = (rg >= 0 && rg < H_) ? 1.f : 0.f;
    Lr[r] *= mrow * ml;
    Mr[r] *= mrow;
    Rr[r] *= mrow * mr;
  }

  const int cblk = c >> 4, crow = c & 15;
  const int tbase = cblk * 2048 + crow * 16 + q * 4;  // ushort units
#pragma unroll
  for (int r = 0; r < 8; ++r) {
    const float t0 = Lr[r],   t1 = Mr[r][0],   t2 = Mr[r][1],   t3 = Mr[r][2],   t4 = Mr[r][3],   t5 = Rr[r];
    const float c0 = Lr[r+1], c1 = Mr[r+1][0], c2 = Mr[r+1][1], c3 = Mr[r+1][2], c4 = Mr[r+1][3], c5 = Rr[r+1];
    const float b0 = Lr[r+2], b1 = Mr[r+2][0], b2 = Mr[r+2][1], b3 = Mr[r+2][2], b4 = Mr[r+2][3], b5 = Rr[r+2];

    float s0 = t0 * k03.x;
    s0 = fmaf(t1, k03.y, s0); s0 = fmaf(t2, k03.z, s0);
    s0 = fmaf(c0, k03.w, s0); s0 = fmaf(c1, k47.x, s0);
    s0 = fmaf(c2, k47.y, s0); s0 = fmaf(b0, k47.z, s0);
    s0 = fmaf(b1, k47.w, s0); s0 = fmaf(b2, k8,    s0);
    float s1 = t1 * k03.x;
    s1 = fmaf(t2, k03.y, s1); s1 = fmaf(t3, k03.z, s1);
    s1 = fmaf(c1, k03.w, s1); s1 = fmaf(c2, k47.x, s1);
    s1 = fmaf(c3, k47.y, s1); s1 = fmaf(b1, k47.z, s1);
    s1 = fmaf(b2, k47.w, s1); s1 = fmaf(b3, k8,    s1);
    float s2 = t2 * k03.x;
    s2 = fmaf(t3, k03.y, s2); s2 = fmaf(t4, k03.z, s2);
    s2 = fmaf(c2, k03.w, s2); s2 = fmaf(c3, k47.x, s2);
    s2 = fmaf(c4, k47.y, s2); s2 = fmaf(b2, k47.z, s2);
    s2 = fmaf(b3, k47.w, s2); s2 = fmaf(b4, k8,    s2);
    float s3 = t3 * k03.x;
    s3 = fmaf(t4, k03.y, s3); s3 = fmaf(t5, k03.z, s3);
    s3 = fmaf(c3, k03.w, s3); s3 = fmaf(c4, k47.x, s3);
    s3 = fmaf(c5, k47.y, s3); s3 = fmaf(b3, k47.z, s3);
    s3 = fmaf(b4, k47.w, s3); s3 = fmaf(b5, k8,    s3);

    uint2v tq, fq;
    tq.x = f2bf(lrelu(s0)) | (f2bf(lrelu(s1)) << 16);
    tq.y = f2bf(lrelu(s2)) | (f2bf(lrelu(s3)) << 16);
    fq.x = f2bf(c1) | (f2bf(c2) << 16);   // center taps (row y0+r, unmasked)
    fq.y = f2bf(c3) | (f2bf(c4) << 16);
    *(uint2v*)&Tq[tbase + r * 256] = tq;
    *(uint2v*)&Fq[tbase + r * 256] = fq;
  }
  __syncthreads();

  // ================= Phase 2: MFMA channel mix =================
  const int lane = tid & 63, wid = tid >> 6;
  const int nl = lane & 15, g = lane >> 4;
  const int ochunk = wid * 16;

  union AF { bf16x8 v; unsigned short u[8]; };
  AF a0, a1;
  {
    const float* wr = Wc + (ochunk + nl) * 64 + 4 * g;
    const float4 w00 = *(const float4*)(wr);
    const float4 w01 = *(const float4*)(wr + 16);
    const float4 w10 = *(const float4*)(wr + 32);
    const float4 w11 = *(const float4*)(wr + 48);
    a0.u[0]=f2bf(w00.x); a0.u[1]=f2bf(w00.y); a0.u[2]=f2bf(w00.z); a0.u[3]=f2bf(w00.w);
    a0.u[4]=f2bf(w01.x); a0.u[5]=f2bf(w01.y); a0.u[6]=f2bf(w01.z); a0.u[7]=f2bf(w01.w);
    a1.u[0]=f2bf(w10.x); a1.u[1]=f2bf(w10.y); a1.u[2]=f2bf(w10.z); a1.u[3]=f2bf(w10.w);
    a1.u[4]=f2bf(w11.x); a1.u[5]=f2bf(w11.y); a1.u[6]=f2bf(w11.z); a1.u[7]=f2bf(w11.w);
  }

  const unsigned t_lds = (unsigned)(uintptr_t)(&Tq[0]) + (unsigned)(lane * 8);
  const unsigned f_lds = (unsigned)(uintptr_t)(&Fq[0]) + (unsigned)(lane * 8) + (unsigned)(wid * 4096);

  f32x4 acc[8];
#pragma unroll
  for (int nt = 0; nt < 8; ++nt) acc[nt] = (f32x4){0.f, 0.f, 0.f, 0.f};

  union BU { bf16x8 v; uint2v qv[2]; };
#pragma unroll
  for (int nt = 0; nt < 8; ++nt) {
    uint2v r0, r1, r2, r3;
    asm volatile("ds_read_b64_tr_b16 %0, %1 offset:%2" : "=v"(r0) : "v"(t_lds), "i"(nt * 512));
    asm volatile("ds_read_b64_tr_b16 %0, %1 offset:%2" : "=v"(r1) : "v"(t_lds), "i"(4096 + nt * 512));
    asm volatile("ds_read_b64_tr_b16 %0, %1 offset:%2" : "=v"(r2) : "v"(t_lds), "i"(8192 + nt * 512));
    asm volatile("ds_read_b64_tr_b16 %0, %1 offset:%2" : "=v"(r3) : "v"(t_lds), "i"(12288 + nt * 512));
    asm volatile("s_waitcnt lgkmcnt(0)" ::: "memory");
    __builtin_amdgcn_sched_barrier(0);
    BU bu0, bu1;
    bu0.qv[0] = r0; bu0.qv[1] = r1;   // k = 4g+j  and  16+4g+j
    bu1.qv[0] = r2; bu1.qv[1] = r3;   // k = 32+4g+j and 48+4g+j
    acc[nt] = __builtin_amdgcn_mfma_f32_16x16x32_bf16(a0.v, bu0.v, acc[nt], 0, 0, 0);
    acc[nt] = __builtin_amdgcn_mfma_f32_16x16x32_bf16(a1.v, bu1.v, acc[nt], 0, 0, 0);
  }

  // ================= Epilogue: + bias + F*att from LDS =================
  const int ob = ochunk + 4 * g;
  const float4 bcv = *(const float4*)(bc + ob);
  const float4 atv = *(const float4*)(attp + ob);
  float* __restrict__ outb = out + (size_t)(b * 64) * HW_;
#pragma unroll
  for (int nt = 0; nt < 8; ++nt) {
    uint2v fr;
    asm volatile("ds_read_b64_tr_b16 %0, %1 offset:%2" : "=v"(fr) : "v"(f_lds), "i"(nt * 512));
    asm volatile("s_waitcnt lgkmcnt(0)" ::: "memory");
    __builtin_amdgcn_sched_barrier(0);
    const float f0 = __uint_as_float((fr.x & 0xffffu) << 16);
    const float f1 = __uint_as_float((fr.x >> 16) << 16);
    const float f2 = __uint_as_float((fr.y & 0xffffu) << 16);
    const float f3 = __uint_as_float((fr.y >> 16) << 16);
    const int off = (y0 + nt) * W_ + x0 + nl;
    outb[(size_t)(ob + 0) * HW_ + off] = acc[nt][0] + bcv.x + f0 * atv.x;
    outb[(size_t)(ob + 1) * HW_ + off] = acc[nt][1] + bcv.y + f1 * atv.y;
    outb[(size_t)(ob + 2) * HW_ + off] = acc[nt][2] + bcv.z + f2 * atv.z;
    outb[(size_t)(ob + 3) * HW_ + off] = acc[nt][3] + bcv.w + f3 * atv.w;
  }
}

extern "C" void kernel_launch(void* const* d_in, const int* in_sizes, int n_in,
                              void* d_out, int out_size, void* d_ws, size_t ws_size,
                              hipStream_t stream) {
  const float* feat = (const float*)d_in[0];
  const float* deg  = (const float*)d_in[1];
  const float* W1   = (const float*)d_in[2];
  const float* W2   = (const float*)d_in[3];
  const float* Wc   = (const float*)d_in[4];
  const float* bc   = (const float*)d_in[5];
  const float* Wd1  = (const float*)d_in[6];
  const float* Wd2  = (const float*)d_in[7];
  float* out = (float*)d_out;
  float* ws  = (float*)d_ws;

  prep_kernel<<<dim3(B_), dim3(64), 0, stream>>>(deg, W1, W2, Wd1, Wd2, ws);
  main_kernel<<<dim3(3200), dim3(256), 0, stream>>>(feat, Wc, bc, ws, out);
}

// Round 10
// 71.740 us; speedup vs baseline: 1.4792x; 1.0841x over previous
//
#include <hip/hip_runtime.h>
#include <hip/hip_bf16.h>
#include <math.h>

#define SLOPE 0.1f
#define B_ 16
#define C_ 64
#define H_ 160
#define W_ 160
#define HW_ (H_*W_)

typedef short bf16x8 __attribute__((ext_vector_type(8)));
typedef float f32x4  __attribute__((ext_vector_type(4)));
typedef unsigned int uint2v __attribute__((ext_vector_type(2)));

__device__ __forceinline__ float lrelu(float x) { return fmaxf(x, SLOPE * x); }
__device__ __forceinline__ unsigned f2bf(float x) {
  union { float f; unsigned u; } c; c.f = x;
  return (c.u + 0x7fffu + ((c.u >> 16) & 1u)) >> 16;
}
__device__ __forceinline__ float bf2f(unsigned short u) {
  union { unsigned u; float f; } c; c.u = ((unsigned)u) << 16; return c.f;
}

__device__ __forceinline__ void gl2lds16(const void* g, void* l) {
  __builtin_amdgcn_global_load_lds(
      (const __attribute__((address_space(1))) void*)g,
      (__attribute__((address_space(3))) void*)l, 16, 0, 0);
}

// ws layout: [0,1024) floats: att[b][c]; bytes [4096, 4096+16*1280): k bf16 [b][64][10]
__global__ __launch_bounds__(64) void prep_kernel(
    const float* __restrict__ deg,
    const float* __restrict__ W1,
    const float* __restrict__ W2,
    const float* __restrict__ Wd1,
    const float* __restrict__ Wd2,
    float* __restrict__ ws) {
  const int b = blockIdx.x;   // 0..15
  const int j = threadIdx.x;  // 0..63
  __shared__ float sd[64], sh[64], sa[8];
  sd[j] = deg[b * 64 + j];
  __syncthreads();

  float acc = 0.f;
  for (int i = 0; i < 64; ++i) acc = fmaf(sd[i], W1[j * 64 + i], acc);
  sh[j] = lrelu(acc);

  if (j < 8) {
    float s = 0.f;
    for (int i = 0; i < 64; ++i) s = fmaf(sd[i], Wd1[j * 64 + i], s);
    sa[j] = lrelu(s);
  }
  __syncthreads();

  float kv[9];
#pragma unroll
  for (int t = 0; t < 9; ++t) kv[t] = 0.f;
  for (int l = 0; l < 64; ++l) {
    float hl = sh[l];
#pragma unroll
    for (int t = 0; t < 9; ++t) kv[t] = fmaf(hl, W2[(j * 9 + t) * 64 + l], kv[t]);
  }
  unsigned short* kw = (unsigned short*)(ws + 1024) + (b * 64 + j) * 10;
#pragma unroll
  for (int t = 0; t < 9; ++t) kw[t] = (unsigned short)f2bf(kv[t]);
  kw[9] = 0;

  float s2 = 0.f;
#pragma unroll
  for (int r = 0; r < 8; ++r) s2 = fmaf(Wd2[j * 8 + r], sa[r], s2);
  ws[b * 64 + j] = 1.f / (1.f + __expf(-s2));
}

// Tile = 8 rows x 16 cols (128 px). 4 channel-groups of 16, double-buffered
// global_load_lds staging (S), counted vmcnt(4) pipeline (never drained
// in-loop). Conv reads LDS only; per-group bf16 T/F subtiles feed
// mfma_16x16x32 (upper k-half zero-padded). Residual folded into MFMA via
// diagonal att matrix against F. LDS 40.7 KB -> 4 blocks/CU.
__global__ __launch_bounds__(256, 4) void main_kernel(
    const float* __restrict__ feat,
    const float* __restrict__ Wc,
    const float* __restrict__ bc,
    const float* __restrict__ ws,
    float* __restrict__ out) {
  __shared__ __align__(16) float S[2][16][244];            // 31,232 B
  __shared__ __align__(16) unsigned short Tt[2048];        //  4,096 B
  __shared__ __align__(16) unsigned short Ff[2048];        //  4,096 B
  __shared__ __align__(16) unsigned short Kl[640];         //  1,280 B

  // Chunked XCD swizzle (3200 % 8 == 0).
  const int rb  = blockIdx.x;
  const int bid = (rb & 7) * 400 + (rb >> 3);
  const int b   = bid / 200;
  const int rem = bid - b * 200;
  const int ty  = rem / 10, tx = rem - ty * 10;
  const int x0 = tx * 16, y0 = ty * 8;
  const int tid = threadIdx.x;
  const int lane = tid & 63, wid = tid >> 6;

  const float* __restrict__ attp  = ws + b * 64;
  const char*  __restrict__ kb8   = (const char*)(ws + 1024) + b * 1280;
  const float* __restrict__ plane = feat + (size_t)(b * 64) * HW_;

  // conv thread ids
  const int ci = tid >> 4;          // channel-in-group 0..15
  const int q  = (tid >> 2) & 3;    // x-quad
  const int h  = tid & 3;           // row-pair
  // mfma thread ids
  const int nl = lane & 15, kg = lane >> 4;
  const int ochunk = wid * 16;

  // stage lane map: lane -> (row 0..9, 16B chunk 0..5); lanes 60-63 masked.
  const int srow = lane / 6;
  const int schk = lane - srow * 6;
  const int grow = min(max(y0 + srow - 1, 0), H_ - 1);
  const int gcol = min(max(x0 - 4 + schk * 4, 0), W_ - 4);
  const float* sp0 = plane + grow * W_ + gcol;

  // ---- compiler-visible preloads (ALL before any async gl2lds) ----
  union AF { bf16x8 v; unsigned short u[8]; };
  AF a[4];
#pragma unroll
  for (int g = 0; g < 4; ++g) {
    const float4 w = *(const float4*)(Wc + (ochunk + nl) * 64 + g * 16 + 4 * kg);
    a[g].u[0] = (unsigned short)f2bf(w.x); a[g].u[1] = (unsigned short)f2bf(w.y);
    a[g].u[2] = (unsigned short)f2bf(w.z); a[g].u[3] = (unsigned short)f2bf(w.w);
    a[g].u[4] = 0; a[g].u[5] = 0; a[g].u[6] = 0; a[g].u[7] = 0;
  }
  AF a2;
  {
    const unsigned short ab = (unsigned short)f2bf(attp[ochunk + nl]);
#pragma unroll
    for (int j = 0; j < 4; ++j) a2.u[j] = (nl == 4 * kg + j) ? ab : (unsigned short)0;
    a2.u[4] = 0; a2.u[5] = 0; a2.u[6] = 0; a2.u[7] = 0;
  }
  const float4 bcv = *(const float4*)(bc + ochunk + 4 * kg);

  asm volatile("s_waitcnt vmcnt(0)" ::: "memory");  // clean vmcnt baseline

  // ---- K stage (wave 0 only: 2 insts) + group-0 stage ----
  if (wid == 0) {
    gl2lds16(kb8 + lane * 16, &Kl[0]);
    if (lane < 16) gl2lds16(kb8 + 1024 + lane * 16, &Kl[512]);
  }
#define STAGE(g, bf) \
  if (lane < 60) { \
    const float* s_ = sp0 + (size_t)((g) * 16 + wid * 4) * HW_; \
    gl2lds16(s_,              &S[bf][wid * 4 + 0][0]); \
    gl2lds16(s_ + 1 * HW_,    &S[bf][wid * 4 + 1][0]); \
    gl2lds16(s_ + 2 * HW_,    &S[bf][wid * 4 + 2][0]); \
    gl2lds16(s_ + 3 * HW_,    &S[bf][wid * 4 + 3][0]); \
  }
  STAGE(0, 0);

  f32x4 acc[8];
#pragma unroll
  for (int nt = 0; nt < 8; ++nt) acc[nt] = (f32x4){0.f, 0.f, 0.f, 0.f};

  // conv edge masks (zero the out-of-image taps)
  const float mlz = (x0 == 0 && q == 0) ? 0.f : 1.f;        // local col 3
  const float mrz = (x0 == W_ - 16 && q == 3) ? 0.f : 1.f;  // local col 8

  const unsigned t_base = (unsigned)(uintptr_t)&Tt[0] + (unsigned)(lane * 8);
  const unsigned f_base = (unsigned)(uintptr_t)&Ff[0] + (unsigned)(lane * 8);
  union BU { bf16x8 v; uint2v qv[2]; };

#pragma unroll
  for (int g = 0; g < 4; ++g) {
    const int bf = g & 1;
    if (g < 3) { STAGE(g + 1, bf ^ 1); }
    if (g < 3) asm volatile("s_waitcnt vmcnt(4)" ::: "memory");
    else       asm volatile("s_waitcnt vmcnt(0)" ::: "memory");
    __builtin_amdgcn_s_barrier();
    __builtin_amdgcn_sched_barrier(0);

    // ---- conv(g) from S[bf] ----
    float kk[9];
#pragma unroll
    for (int t = 0; t < 9; ++t) kk[t] = bf2f(Kl[(g * 16 + ci) * 10 + t]);

    float rv[4][9];
#pragma unroll
    for (int rr = 0; rr < 4; ++rr) {
      const float* sp = &S[bf][ci][(2 * h + rr) * 24 + 4 * q];
      const f32x4 v0 = *(const f32x4*)sp;
      const f32x4 v1 = *(const f32x4*)(sp + 4);
      rv[rr][0] = v0[0]; rv[rr][1] = v0[1]; rv[rr][2] = v0[2];
      rv[rr][3] = v0[3] * mlz;
      rv[rr][4] = v1[0]; rv[rr][5] = v1[1]; rv[rr][6] = v1[2]; rv[rr][7] = v1[3];
      rv[rr][8] = sp[8] * mrz;
    }

#pragma unroll
    for (int rr = 0; rr < 2; ++rr) {
      const int srw = 2 * h + rr;  // tile row 0..7
      const float mt = (srw == 0 && y0 == 0) ? 0.f : 1.f;
      const float mb = (srw == 7 && y0 == H_ - 8) ? 0.f : 1.f;
      float sv[4], fv[4];
#pragma unroll
      for (int j = 0; j < 4; ++j) {
        float ts = fmaf(rv[rr][j + 5], kk[2], fmaf(rv[rr][j + 4], kk[1], rv[rr][j + 3] * kk[0]));
        float cs = fmaf(rv[rr + 1][j + 5], kk[5], fmaf(rv[rr + 1][j + 4], kk[4], rv[rr + 1][j + 3] * kk[3]));
        float bs = fmaf(rv[rr + 2][j + 5], kk[8], fmaf(rv[rr + 2][j + 4], kk[7], rv[rr + 2][j + 3] * kk[6]));
        sv[j] = fmaf(mt, ts, fmaf(mb, bs, cs));
        fv[j] = rv[rr + 1][j + 4];  // center tap (always in-image)
      }
      uint2v tq, fq;
      tq.x = f2bf(lrelu(sv[0])) | (f2bf(lrelu(sv[1])) << 16);
      tq.y = f2bf(lrelu(sv[2])) | (f2bf(lrelu(sv[3])) << 16);
      fq.x = f2bf(fv[0]) | (f2bf(fv[1]) << 16);
      fq.y = f2bf(fv[2]) | (f2bf(fv[3]) << 16);
      const int tidx = srw * 256 + ci * 16 + 4 * q;
      *(uint2v*)&Tt[tidx] = tq;
      *(uint2v*)&Ff[tidx] = fq;
    }

    asm volatile("s_waitcnt lgkmcnt(0)" ::: "memory");
    __builtin_amdgcn_s_barrier();
    __builtin_amdgcn_sched_barrier(0);

    // ---- MFMA(g): k-slice accumulate (upper k-half zero) ----
#pragma unroll
    for (int nt = 0; nt < 8; ++nt) {
      uint2v r0;
      asm volatile("ds_read_b64_tr_b16 %0, %1 offset:%2" : "=v"(r0) : "v"(t_base), "i"(nt * 512));
      asm volatile("s_waitcnt lgkmcnt(0)" ::: "memory");
      __builtin_amdgcn_sched_barrier(0);
      BU bu; bu.qv[0] = r0; bu.qv[1] = (uint2v){0u, 0u};
      acc[nt] = __builtin_amdgcn_mfma_f32_16x16x32_bf16(a[g].v, bu.v, acc[nt], 0, 0, 0);
    }
    if (wid == g) {  // residual: diag(att) x F for this wave's o-chunk
#pragma unroll
      for (int nt = 0; nt < 8; ++nt) {
        uint2v r0;
        asm volatile("ds_read_b64_tr_b16 %0, %1 offset:%2" : "=v"(r0) : "v"(f_base), "i"(nt * 512));
        asm volatile("s_waitcnt lgkmcnt(0)" ::: "memory");
        __builtin_amdgcn_sched_barrier(0);
        BU bu; bu.qv[0] = r0; bu.qv[1] = (uint2v){0u, 0u};
        acc[nt] = __builtin_amdgcn_mfma_f32_16x16x32_bf16(a2.v, bu.v, acc[nt], 0, 0, 0);
      }
    }
    __builtin_amdgcn_s_barrier();
    __builtin_amdgcn_sched_barrier(0);
  }
#undef STAGE

  // ---- epilogue: + bias, store ----
  const int ob = ochunk + 4 * kg;
  float* __restrict__ outb = out + (size_t)(b * 64) * HW_;
#pragma unroll
  for (int nt = 0; nt < 8; ++nt) {
    const int off = (y0 + nt) * W_ + x0 + nl;
    outb[(size_t)(ob + 0) * HW_ + off] = acc[nt][0] + bcv.x;
    outb[(size_t)(ob + 1) * HW_ + off] = acc[nt][1] + bcv.y;
    outb[(size_t)(ob + 2) * HW_ + off] = acc[nt][2] + bcv.z;
    outb[(size_t)(ob + 3) * HW_ + off] = acc[nt][3] + bcv.w;
  }
}

extern "C" void kernel_launch(void* const* d_in, const int* in_sizes, int n_in,
                              void* d_out, int out_size, void* d_ws, size_t ws_size,
                              hipStream_t stream) {
  const float* feat = (const float*)d_in[0];
  const float* deg  = (const float*)d_in[1];
  const float* W1   = (const float*)d_in[2];
  const float* W2   = (const float*)d_in[3];
  const float* Wc   = (const float*)d_in[4];
  const float* bc   = (const float*)d_in[5];
  const float* Wd1  = (const float*)d_in[6];
  const float* Wd2  = (const float*)d_in[7];
  float* out = (float*)d_out;
  float* ws  = (float*)d_ws;

  prep_kernel<<<dim3(B_), dim3(64), 0, stream>>>(deg, W1, W2, Wd1, Wd2, ws);
  main_kernel<<<dim3(3200), dim3(256), 0, stream>>>(feat, Wc, bc, ws, out);
}